// Round 16
// baseline (265.051 us; speedup 1.0000x reference)
//
#include <hip/hip_runtime.h>
#include <hip/hip_bf16.h>
#include <hip/hip_fp16.h>

typedef float f32x4 __attribute__((ext_vector_type(4)));
typedef unsigned int u32;
typedef u32 u32x4 __attribute__((ext_vector_type(4)));
typedef __bf16 bf16x8 __attribute__((ext_vector_type(8)));
typedef short s16x8 __attribute__((ext_vector_type(8)));
typedef unsigned short u16;

#define HWSZ 16384
#define NPIX 131072

// ws byte offsets
#define XT_OFF    0u          // u16(bf16)[NPIX*64]  x transposed to NHWC (16.78 MB)
#define PART_OFF  33554432u   // float[8192*128]  per-block BN partials (4 MB)
#define WB_OFF    42991616u   // u16(bf16)[64*576]  deform_w, [o][k2*64+c]
#define STATS_OFF 43106816u   // float[256]: (unused)[128], scale[64], shift[64]
#define WO_OFF    43107840u   // u16(bf16)[32*576]  offset_w padded, [oc][k2*64+c]

__device__ inline u32 pkbf(float lo, float hi) {
  u16 l = __builtin_bit_cast(u16, __float2bfloat16(lo));
  u16 h = __builtin_bit_cast(u16, __float2bfloat16(hi));
  return (u32)l | ((u32)h << 16);
}
__device__ inline float bflo(u32 u) { return __builtin_bit_cast(float, u << 16); }
__device__ inline float bfhi(u32 u) { return __builtin_bit_cast(float, u & 0xFFFF0000u); }

// ---- prep: reorder/convert weights to bf16 ----
__global__ void kprep(const float* __restrict__ dw, const float* __restrict__ ow,
                      u16* __restrict__ Wb, u16* __restrict__ Wo) {
  int t = blockIdx.x * 256 + threadIdx.x;
  if (t < 36864) {                      // deform_w (64,64,3,3) -> Wb[o][k2*64+c] bf16
    int o = t / 576, r = t % 576;
    int c = r / 9, k2 = r % 9;
    __hip_bfloat16 h = __float2bfloat16(dw[t]);
    Wb[o * 576 + k2 * 64 + c] = __builtin_bit_cast(u16, h);
  } else if (t < 55296) {               // offset_w (18,64,3,3) -> Wo[oc][k2*64+c], pad to 32
    int t2 = t - 36864;
    int oc = t2 / 576, r = t2 % 576;
    int c = r / 9, k2 = r % 9;
    float v = (oc < 18) ? ow[(oc * 64 + c) * 9 + k2] : 0.f;
    __hip_bfloat16 h = __float2bfloat16(v);
    Wo[oc * 576 + k2 * 64 + c] = __builtin_bit_cast(u16, h);
  }
}

// ---- NCHW f32 -> NHWC bf16 transpose of x (vectorized 16B stores) ----
__global__ void ktrans(const float* __restrict__ x, u16* __restrict__ xt) {
  __shared__ float tile[64][65];
  int blk = blockIdx.x;
  int b = blk >> 8, hwT = (blk & 255) * 64;
  int tid = threadIdx.x;
  int tx = tid & 63, ty = tid >> 6;
  const float* xp = x + (size_t)b * 64 * HWSZ;
#pragma unroll
  for (int r = 0; r < 16; ++r) {
    int c = r * 4 + ty;
    tile[c][tx] = xp[c * HWSZ + hwT + tx];
  }
  __syncthreads();
  u16* xo = xt + ((size_t)b * HWSZ + hwT) * 64;
  int o8 = (tid & 7) * 8;
#pragma unroll
  for (int r = 0; r < 2; ++r) {
    int hwl = r * 32 + (tid >> 3);
    u32x4 out;
#pragma unroll
    for (int j = 0; j < 4; ++j)
      out[j] = pkbf(tile[o8 + 2 * j][hwl], tile[o8 + 2 * j + 1][hwl]);
    *(u32x4*)&xo[(size_t)hwl * 64 + o8] = out;
  }
}

// ---- fused: offset-conv GEMM -> offs LDS -> meta -> sampling -> deform GEMM ----
// block: 256 thr = 4 waves; tile = 16 pixels; LDS 20160 B -> 8 blocks/CU
// sampling unit: p = tid>>4 (0..15), oct = (tid>>1)&7, half = tid&1 (tap parity)
__global__ __launch_bounds__(256, 8) void kmain(
    const u16* __restrict__ xt, const u16* __restrict__ Wo,
    const float* __restrict__ offb, const u16* __restrict__ Wb,
    const float* __restrict__ db, float* __restrict__ y,
    float* __restrict__ part) {
  __shared__ u16 S[16 * 576];          // bf16, XOR-swizzled: u16idx ^= (row&7)<<3
  __shared__ u32 mWp[144 * 2];         // per (pix,tap): f16x2 {w00,w01},{w10,w11}
  __shared__ u32 mPos[144];            // pixel_byte(×128) | dxs | dys<<1
  float* OFFT = (float*)S;             // [16][20] floats, aliases S head
  int tid = threadIdx.x;
  int lane = tid & 63, wid = tid >> 6;
  int bid = blockIdx.x;
  int batch = bid & 7, tilei = bid >> 3;
  int base = (batch << 14) + tilei * 16;
  int b = batch;
  int hw0 = base & 16383;
  int h0 = hw0 >> 7, w0 = hw0 & 127;   // 16-px tile lies within row h0

  int p = tid >> 4;                    // pixel 0..15
  int oct = (tid >> 1) & 7;            // channel octet 0..7
  int half = tid & 1;                  // tap parity
  int oct16 = oct << 4, oct8 = oct << 3;
  const char* xb = (const char*)xt;

  // ---- A: im2col S-build (tap-split across thread pairs) ----
  {
    int px = w0 + p;
    auto im2col_tap = [&](int k2) {
      int ky = k2 / 3, kx = k2 % 3;
      int yy = h0 - 1 + ky, xx = px - 1 + kx;
      bool v = ((unsigned)yy < 128u) && ((unsigned)xx < 128u);
      const char* pb =
          v ? xb + (size_t)(((b << 14) + yy * 128 + xx) * 128) + oct16 : xb;
      u32x4 g = *(const u32x4*)pb;
      u32 msk = v ? 0xFFFFFFFFu : 0u;
      u32x4 out;
#pragma unroll
      for (int j = 0; j < 4; ++j) out[j] = g[j] & msk;
      int idx = (p * 576 + k2 * 64 + oct8) ^ ((p & 7) << 3);
      *(u32x4*)&S[idx] = out;
    };
#pragma unroll
    for (int ki = 0; ki < 4; ++ki) im2col_tap(2 * ki + half);
    if (!half) im2col_tap(8);
  }
  s16x8 ofr[18];
  if (wid < 2) {                       // waves 0-1 run offset-conv MFMA (32oc x 16px)
    const u16* wrow = Wo + (wid * 16 + (lane & 15)) * 576 + (lane >> 4) * 8;
#pragma unroll
    for (int kc = 0; kc < 18; ++kc) ofr[kc] = *(const s16x8*)(wrow + kc * 32);
  }
  __syncthreads();

  // ---- B: offset-conv MFMA (waves 0-1; 18 MFMA each) ----
  f32x4 acco = {0.f, 0.f, 0.f, 0.f};
  if (wid < 2) {
#pragma unroll
    for (int kc = 0; kc < 18; ++kc) {
      int row = lane & 15;             // pixel
      int idx = (row * 576 + kc * 32 + (lane >> 4) * 8) ^ ((row & 7) << 3);
      bf16x8 bfr = __builtin_bit_cast(bf16x8, *(const s16x8*)&S[idx]);
      acco = __builtin_amdgcn_mfma_f32_16x16x32_bf16(
          __builtin_bit_cast(bf16x8, ofr[kc]), bfr, acco, 0, 0, 0);
    }
  }
  __syncthreads();

  // ---- C: offs -> OFFT (LDS, aliases dead S head) ----
  if (wid < 2) {
    int pixl = lane & 15;
    int ocb = wid * 16 + (lane >> 4) * 4;
#pragma unroll
    for (int r = 0; r < 4; ++r) {
      int oc = ocb + r;
      if (oc < 18) OFFT[pixl * 20 + oc] = acco[r] + offb[oc];
    }
  }
  __syncthreads();

  // ---- D: per-(pixel,tap) meta (144 tasks) ----
  if (tid < 144) {
    int t = tid;
    int tp = t / 9, k2 = t - tp * 9;
    int pix = base + tp;
    int hw = pix & 16383;
    int hh = hw >> 7, ww = hw & 127;
    float dy = OFFT[tp * 20 + 2 * k2];
    float dx = OFFT[tp * 20 + 2 * k2 + 1];
    float sy = (float)(hh - 1 + k2 / 3) + dy;
    float sx = (float)(ww - 1 + k2 % 3) + dx;
    float fy = floorf(sy), fx = floorf(sx);
    int y0 = (int)fy, x0 = (int)fx;
    float wy1 = sy - fy, wx1 = sx - fx;
    float ay0 = ((unsigned)y0 < 128u) ? 1.f - wy1 : 0.f;
    float ay1 = ((unsigned)(y0 + 1) < 128u) ? wy1 : 0.f;
    float ax0 = ((unsigned)x0 < 128u) ? 1.f - wx1 : 0.f;
    float ax1 = ((unsigned)(x0 + 1) < 128u) ? wx1 : 0.f;
    int y0c = min(max(y0, 0), 127), x0c = min(max(x0, 0), 127);
    int dys = min(max(y0 + 1, 0), 127) - y0c;
    int dxs = min(max(x0 + 1, 0), 127) - x0c;
    mWp[t * 2]     = __builtin_bit_cast(u32, __floats2half2_rn(ay0 * ax0, ay0 * ax1));
    mWp[t * 2 + 1] = __builtin_bit_cast(u32, __floats2half2_rn(ay1 * ax0, ay1 * ax1));
    mPos[t] = (u32)(((b << 14) + y0c * 128 + x0c) * 128) | (u32)dxs | ((u32)dys << 1);
  }
  __syncthreads();

  // ---- E: sampling (tap-split across thread pairs) ----
  {
    auto sample_tap = [&](int k) {
      int t = p * 9 + k;
      u32 wlo = mWp[t * 2], whi = mWp[t * 2 + 1];
      u32 pm = mPos[t];
      u32 dxB = (pm & 1u) << 7;        // 128 B x-step
      u32 dyB = (pm & 2u) << 13;       // 16384 B y-step
      const char* pb = xb + (pm & 0xFFFFFF80u) + oct16;
      u32x4 c00 = *(const u32x4*)pb;
      u32x4 c01 = *(const u32x4*)(pb + dxB);
      u32x4 c10 = *(const u32x4*)(pb + dyB);
      u32x4 c11 = *(const u32x4*)(pb + dyB + dxB);
      __half2 hl = __builtin_bit_cast(__half2, wlo);
      __half2 hh2 = __builtin_bit_cast(__half2, whi);
      float w00 = __low2float(hl), w01 = __high2float(hl);
      float w10 = __low2float(hh2), w11 = __high2float(hh2);
      u32x4 out;
#pragma unroll
      for (int j = 0; j < 4; ++j) {
        float sL = fmaf(w11, bflo(c11[j]), fmaf(w10, bflo(c10[j]),
                   fmaf(w01, bflo(c01[j]), w00 * bflo(c00[j]))));
        float sH = fmaf(w11, bfhi(c11[j]), fmaf(w10, bfhi(c10[j]),
                   fmaf(w01, bfhi(c01[j]), w00 * bfhi(c00[j]))));
        out[j] = pkbf(sL, sH);
      }
      int idx = (p * 576 + k * 64 + oct8) ^ ((p & 7) << 3);
      *(u32x4*)&S[idx] = out;
    };
#pragma unroll
    for (int ki = 0; ki < 4; ++ki) sample_tap(2 * ki + half);
    if (!half) sample_tap(8);
  }

  // A fragments for deform MFMA: wave wid -> o rows wid*16..+15
  s16x8 afr[18];
  {
    const u16* wrow = Wb + (wid * 16 + (lane & 15)) * 576 + (lane >> 4) * 8;
#pragma unroll
    for (int kc = 0; kc < 18; ++kc) afr[kc] = *(const s16x8*)(wrow + kc * 32);
  }
  __syncthreads();

  // ---- F: deform MFMA — 4 o-tiles (one per wave), 18 MFMA each ----
  f32x4 acc = {0.f, 0.f, 0.f, 0.f};
#pragma unroll
  for (int kc = 0; kc < 18; ++kc) {
    int row = lane & 15;               // pixel
    int idx = (row * 576 + kc * 32 + (lane >> 4) * 8) ^ ((row & 7) << 3);
    bf16x8 bfr = __builtin_bit_cast(bf16x8, *(const s16x8*)&S[idx]);
    acc = __builtin_amdgcn_mfma_f32_16x16x32_bf16(
        __builtin_bit_cast(bf16x8, afr[kc]), bfr, acc, 0, 0, 0);
  }

  // ---- G: epilogue — y write + per-wave BN partials (no atomics) ----
  int obase = wid * 16 + (lane >> 4) * 4;
  int pix = base + (lane & 15);
  int hw = pix & 16383;
  float* yp = y + (size_t)b * (64 * HWSZ) + hw;
  float s1[4], s2[4];
#pragma unroll
  for (int r = 0; r < 4; ++r) {
    int o = obase + r;
    float v = acc[r] + db[o];
    yp[(size_t)o * HWSZ] = v;
    s1[r] = v;
    s2[r] = v * v;
  }
#pragma unroll
  for (int m = 1; m < 16; m <<= 1) {
#pragma unroll
    for (int r = 0; r < 4; ++r) {
      s1[r] += __shfl_xor(s1[r], m, 64);
      s2[r] += __shfl_xor(s2[r], m, 64);
    }
  }
  if ((lane & 15) == 0) {
    float* pp = part + (size_t)bid * 128;
#pragma unroll
    for (int r = 0; r < 4; ++r) {
      pp[obase + r] = s1[r];
      pp[64 + obase + r] = s2[r];
    }
  }
}

// ---- BN finalize: reduce 8192-block partials, one block per channel ----
__global__ void kbnf(const float* __restrict__ part, const float* __restrict__ gamma,
                     const float* __restrict__ beta, float* __restrict__ stats) {
  __shared__ float r1[256], r2[256];
  int o = blockIdx.x;
  int tid = threadIdx.x;
  float s1 = 0.f, s2 = 0.f;
  for (int i = tid; i < 8192; i += 256) {
    s1 += part[(size_t)i * 128 + o];
    s2 += part[(size_t)i * 128 + 64 + o];
  }
  r1[tid] = s1; r2[tid] = s2;
  __syncthreads();
  for (int s = 128; s > 0; s >>= 1) {
    if (tid < s) { r1[tid] += r1[tid + s]; r2[tid] += r2[tid + s]; }
    __syncthreads();
  }
  if (tid == 0) {
    float m = r1[0] * (1.f / 131072.f);
    float v = r2[0] * (1.f / 131072.f) - m * m;
    float sc = gamma[o] * rsqrtf(v + 1e-5f);
    stats[128 + o] = sc;
    stats[192 + o] = beta[o] - m * sc;
  }
}

// ---- in-place scale/shift + PReLU on y (= d_out) ----
__global__ void kfinal(float* __restrict__ y, const float* __restrict__ stats,
                       const float* __restrict__ pa) {
  float a = pa[0];
  int total = NPIX * 64 / 4;
  for (int i = blockIdx.x * blockDim.x + threadIdx.x; i < total;
       i += gridDim.x * blockDim.x) {
    int o = (i >> 12) & 63;
    f32x4 v = ((const f32x4*)y)[i];
    float sc = stats[128 + o], sh = stats[192 + o];
#pragma unroll
    for (int j = 0; j < 4; ++j) {
      float t = fmaf(v[j], sc, sh);
      v[j] = t >= 0.f ? t : a * t;
    }
    ((f32x4*)y)[i] = v;
  }
}

extern "C" void kernel_launch(void* const* d_in, const int* in_sizes, int n_in,
                              void* d_out, int out_size, void* d_ws, size_t ws_size,
                              hipStream_t stream) {
  const float* x  = (const float*)d_in[0];
  const float* ow = (const float*)d_in[1];
  const float* ob = (const float*)d_in[2];
  const float* dw = (const float*)d_in[3];
  const float* db = (const float*)d_in[4];
  const float* gm = (const float*)d_in[5];
  const float* bt = (const float*)d_in[6];
  const float* pa = (const float*)d_in[7];
  char* ws = (char*)d_ws;
  u16*   xt    = (u16*)(ws + XT_OFF);
  float* part  = (float*)(ws + PART_OFF);
  u16*   Wb    = (u16*)(ws + WB_OFF);
  u16*   Wo    = (u16*)(ws + WO_OFF);
  float* stats = (float*)(ws + STATS_OFF);
  float* y = (float*)d_out;   // d_out doubles as the pre-BN activation buffer

  kprep<<<216, 256, 0, stream>>>(dw, ow, Wb, Wo);
  ktrans<<<2048, 256, 0, stream>>>(x, xt);
  kmain<<<8192, 256, 0, stream>>>(xt, Wo, ob, Wb, db, y, part);
  kbnf<<<64, 256, 0, stream>>>(part, gm, bt, stats);
  kfinal<<<2048, 256, 0, stream>>>(y, stats, pa);
}

// Round 17
// 132.993 us; speedup vs baseline: 1.9930x; 1.9930x over previous
//
#include <hip/hip_runtime.h>
#include <hip/hip_bf16.h>
#include <hip/hip_fp16.h>

typedef float f32x4 __attribute__((ext_vector_type(4)));
typedef unsigned int u32;
typedef u32 u32x4 __attribute__((ext_vector_type(4)));
typedef __bf16 bf16x8 __attribute__((ext_vector_type(8)));
typedef short s16x8 __attribute__((ext_vector_type(8)));
typedef unsigned short u16;

#define HWSZ 16384
#define NPIX 131072

// ws byte offsets
#define XT_OFF    0u          // u16(bf16)[NPIX*64]  x transposed to NHWC (16.78 MB)
#define PART_OFF  33554432u   // float[4096*128]  per-block BN partials (2 MB)
#define WB_OFF    42991616u   // u16(bf16)[64*576]  deform_w, [o][k2*64+c]
#define STATS_OFF 43106816u   // float[256]: (unused)[128], scale[64], shift[64]
#define WO_OFF    43107840u   // u16(bf16)[32*576]  offset_w padded, [oc][k2*64+c]

__device__ inline u32 pkbf(float lo, float hi) {
  u16 l = __builtin_bit_cast(u16, __float2bfloat16(lo));
  u16 h = __builtin_bit_cast(u16, __float2bfloat16(hi));
  return (u32)l | ((u32)h << 16);
}
__device__ inline float bflo(u32 u) { return __builtin_bit_cast(float, u << 16); }
__device__ inline float bfhi(u32 u) { return __builtin_bit_cast(float, u & 0xFFFF0000u); }

// ---- prep: reorder/convert weights to bf16 ----
__global__ void kprep(const float* __restrict__ dw, const float* __restrict__ ow,
                      u16* __restrict__ Wb, u16* __restrict__ Wo) {
  int t = blockIdx.x * 256 + threadIdx.x;
  if (t < 36864) {                      // deform_w (64,64,3,3) -> Wb[o][k2*64+c] bf16
    int o = t / 576, r = t % 576;
    int c = r / 9, k2 = r % 9;
    __hip_bfloat16 h = __float2bfloat16(dw[t]);
    Wb[o * 576 + k2 * 64 + c] = __builtin_bit_cast(u16, h);
  } else if (t < 55296) {               // offset_w (18,64,3,3) -> Wo[oc][k2*64+c], pad to 32
    int t2 = t - 36864;
    int oc = t2 / 576, r = t2 % 576;
    int c = r / 9, k2 = r % 9;
    float v = (oc < 18) ? ow[(oc * 64 + c) * 9 + k2] : 0.f;
    __hip_bfloat16 h = __float2bfloat16(v);
    Wo[oc * 576 + k2 * 64 + c] = __builtin_bit_cast(u16, h);
  }
}

// ---- NCHW f32 -> NHWC bf16 transpose of x (vectorized 16B stores) ----
__global__ void ktrans(const float* __restrict__ x, u16* __restrict__ xt) {
  __shared__ float tile[64][65];
  int blk = blockIdx.x;
  int b = blk >> 8, hwT = (blk & 255) * 64;
  int tid = threadIdx.x;
  int tx = tid & 63, ty = tid >> 6;
  const float* xp = x + (size_t)b * 64 * HWSZ;
#pragma unroll
  for (int r = 0; r < 16; ++r) {
    int c = r * 4 + ty;
    tile[c][tx] = xp[c * HWSZ + hwT + tx];
  }
  __syncthreads();
  u16* xo = xt + ((size_t)b * HWSZ + hwT) * 64;
  int o8 = (tid & 7) * 8;
#pragma unroll
  for (int r = 0; r < 2; ++r) {
    int hwl = r * 32 + (tid >> 3);
    u32x4 out;
#pragma unroll
    for (int j = 0; j < 4; ++j)
      out[j] = pkbf(tile[o8 + 2 * j][hwl], tile[o8 + 2 * j + 1][hwl]);
    *(u32x4*)&xo[(size_t)hwl * 64 + o8] = out;
  }
}

// ---- fused, tap-pipelined: per-tap staging (8KB dbuf) + MFMA accumulate ----
// block: 256 thr = 4 waves; tile = 32 pixels
// LDS: S2 8192 + OFFT 2560 + mWp 2304 + mPos 1152 = 14208 B -> LDS allows 11 blk/CU
__global__ __launch_bounds__(256, 6) void kmain(
    const u16* __restrict__ xt, const u16* __restrict__ Wo,
    const float* __restrict__ offb, const u16* __restrict__ Wb,
    const float* __restrict__ db, float* __restrict__ y,
    float* __restrict__ part) {
  __shared__ u16 S2[2][32 * 64];       // per-tap staging, XOR-swizzled per 64ch row
  __shared__ float OFFT[32 * 20];
  __shared__ u32 mWp[288 * 2];         // per (pix,tap): f16x2 {w00,w01},{w10,w11}
  __shared__ u32 mPos[288];            // pixel_byte(×128) | dxs | dys<<1
  int tid = threadIdx.x;
  int lane = tid & 63, wid = tid >> 6;
  int bid = blockIdx.x;
  int batch = bid & 7, tilei = bid >> 3;
  int base = (batch << 14) + tilei * 32;
  int b = batch;
  int hw0 = base & 16383;
  int h0 = hw0 >> 7, w0 = hw0 & 127;   // 32-px tile lies within row h0

  int oct = lane & 7;
  int p = wid * 8 + (lane >> 3);       // this thread's pixel (0..31)
  int oct16 = oct << 4, oct8 = oct << 3;
  int sidx = (p * 64 + oct8) ^ ((p & 7) << 3);   // S2 write slot (u16 idx)
  int q8 = (lane >> 4) * 8;
  const char* xb = (const char*)xt;

  int mr = wid >> 1, nr = wid & 1;     // offc quadrant
  int orow_o = mr * 16 + (lane & 15);  // Wo row
  int brow_o = nr * 16 + (lane & 15);  // pixel row for offc B

  // ---- phase 1: offset-conv GEMM, tap-pipelined ----
  f32x4 acco = {0.f, 0.f, 0.f, 0.f};
#pragma unroll
  for (int k = 0; k < 9; ++k) {
    {  // im2col tap k (branchless copy)
      int yy = h0 - 1 + k / 3, xx = w0 + p - 1 + k % 3;
      bool v = ((unsigned)yy < 128u) && ((unsigned)xx < 128u);
      const char* pb =
          v ? xb + (size_t)(((b << 14) + yy * 128 + xx) * 128) + oct16 : xb;
      u32x4 g = *(const u32x4*)pb;
      u32 msk = v ? 0xFFFFFFFFu : 0u;
      u32x4 out;
#pragma unroll
      for (int j = 0; j < 4; ++j) out[j] = g[j] & msk;
      *(u32x4*)&S2[k & 1][sidx] = out;
    }
    __syncthreads();
#pragma unroll
    for (int h = 0; h < 2; ++h) {
      int kc = 2 * k + h;
      s16x8 a = *(const s16x8*)(Wo + orow_o * 576 + kc * 32 + q8);
      int idx = (brow_o * 64 + h * 32 + q8) ^ ((brow_o & 7) << 3);
      bf16x8 bb = __builtin_bit_cast(bf16x8, *(const s16x8*)&S2[k & 1][idx]);
      acco = __builtin_amdgcn_mfma_f32_16x16x32_bf16(
          __builtin_bit_cast(bf16x8, a), bb, acco, 0, 0, 0);
    }
  }
  __syncthreads();

  // ---- offs -> OFFT ----
  {
    int pixl = nr * 16 + (lane & 15);
    int ocb = mr * 16 + (lane >> 4) * 4;
#pragma unroll
    for (int r = 0; r < 4; ++r) {
      int oc = ocb + r;
      if (oc < 18) OFFT[pixl * 20 + oc] = acco[r] + offb[oc];
    }
  }
  __syncthreads();

  // ---- meta: per-(pixel,tap), 288 tasks ----
  for (int t = tid; t < 288; t += 256) {
    int tp = t / 9, k2 = t - tp * 9;
    int pix = base + tp;
    int hw = pix & 16383;
    int hh = hw >> 7, ww = hw & 127;
    float dy = OFFT[tp * 20 + 2 * k2];
    float dx = OFFT[tp * 20 + 2 * k2 + 1];
    float sy = (float)(hh - 1 + k2 / 3) + dy;
    float sx = (float)(ww - 1 + k2 % 3) + dx;
    float fy = floorf(sy), fx = floorf(sx);
    int y0 = (int)fy, x0 = (int)fx;
    float wy1 = sy - fy, wx1 = sx - fx;
    float ay0 = ((unsigned)y0 < 128u) ? 1.f - wy1 : 0.f;
    float ay1 = ((unsigned)(y0 + 1) < 128u) ? wy1 : 0.f;
    float ax0 = ((unsigned)x0 < 128u) ? 1.f - wx1 : 0.f;
    float ax1 = ((unsigned)(x0 + 1) < 128u) ? wx1 : 0.f;
    int y0c = min(max(y0, 0), 127), x0c = min(max(x0, 0), 127);
    int dys = min(max(y0 + 1, 0), 127) - y0c;
    int dxs = min(max(x0 + 1, 0), 127) - x0c;
    mWp[t * 2]     = __builtin_bit_cast(u32, __floats2half2_rn(ay0 * ax0, ay0 * ax1));
    mWp[t * 2 + 1] = __builtin_bit_cast(u32, __floats2half2_rn(ay1 * ax0, ay1 * ax1));
    mPos[t] = (u32)(((b << 14) + y0c * 128 + x0c) * 128) | (u32)dxs | ((u32)dys << 1);
  }
  __syncthreads();

  // ---- phase 2: deform GEMM, tap-pipelined sampling ----
  f32x4 acc0 = {0.f, 0.f, 0.f, 0.f}, acc1 = {0.f, 0.f, 0.f, 0.f};
  int orow_d = wid * 16 + (lane & 15);
#pragma unroll
  for (int k = 0; k < 9; ++k) {
    {  // sample tap k: 4 bf16 gathers + f32 interp
      int t = p * 9 + k;
      u32 wlo = mWp[t * 2], whi = mWp[t * 2 + 1];
      u32 pm = mPos[t];
      u32 dxB = (pm & 1u) << 7;        // 128 B x-step
      u32 dyB = (pm & 2u) << 13;       // 16384 B y-step
      const char* pb = xb + (pm & 0xFFFFFF80u) + oct16;
      u32x4 c00 = *(const u32x4*)pb;
      u32x4 c01 = *(const u32x4*)(pb + dxB);
      u32x4 c10 = *(const u32x4*)(pb + dyB);
      u32x4 c11 = *(const u32x4*)(pb + dyB + dxB);
      __half2 hl = __builtin_bit_cast(__half2, wlo);
      __half2 hh2 = __builtin_bit_cast(__half2, whi);
      float w00 = __low2float(hl), w01 = __high2float(hl);
      float w10 = __low2float(hh2), w11 = __high2float(hh2);
      u32x4 out;
#pragma unroll
      for (int j = 0; j < 4; ++j) {
        float sL = fmaf(w11, bflo(c11[j]), fmaf(w10, bflo(c10[j]),
                   fmaf(w01, bflo(c01[j]), w00 * bflo(c00[j]))));
        float sH = fmaf(w11, bfhi(c11[j]), fmaf(w10, bfhi(c10[j]),
                   fmaf(w01, bfhi(c01[j]), w00 * bfhi(c00[j]))));
        out[j] = pkbf(sL, sH);
      }
      *(u32x4*)&S2[k & 1][sidx] = out;
    }
    __syncthreads();
#pragma unroll
    for (int h = 0; h < 2; ++h) {
      int kc = 2 * k + h;
      s16x8 a = *(const s16x8*)(Wb + orow_d * 576 + kc * 32 + q8);
      {
        int r0 = lane & 15;
        int idx = (r0 * 64 + h * 32 + q8) ^ ((r0 & 7) << 3);
        bf16x8 bb = __builtin_bit_cast(bf16x8, *(const s16x8*)&S2[k & 1][idx]);
        acc0 = __builtin_amdgcn_mfma_f32_16x16x32_bf16(
            __builtin_bit_cast(bf16x8, a), bb, acc0, 0, 0, 0);
      }
      {
        int r1 = 16 + (lane & 15);
        int idx = (r1 * 64 + h * 32 + q8) ^ ((r1 & 7) << 3);
        bf16x8 bb = __builtin_bit_cast(bf16x8, *(const s16x8*)&S2[k & 1][idx]);
        acc1 = __builtin_amdgcn_mfma_f32_16x16x32_bf16(
            __builtin_bit_cast(bf16x8, a), bb, acc1, 0, 0, 0);
      }
    }
  }

  // ---- epilogue: y write + per-block BN partials (no atomics) ----
  int obase = wid * 16 + (lane >> 4) * 4;
  float s1[4] = {0, 0, 0, 0}, s2[4] = {0, 0, 0, 0};
#pragma unroll
  for (int nf = 0; nf < 2; ++nf) {
    int pix = base + nf * 16 + (lane & 15);
    int hw = pix & 16383;
    float* yp = y + (size_t)b * (64 * HWSZ) + hw;
    f32x4 a = nf ? acc1 : acc0;
#pragma unroll
    for (int r = 0; r < 4; ++r) {
      int o = obase + r;
      float v = a[r] + db[o];
      yp[(size_t)o * HWSZ] = v;
      s1[r] += v;
      s2[r] += v * v;
    }
  }
#pragma unroll
  for (int m = 1; m < 16; m <<= 1) {
#pragma unroll
    for (int r = 0; r < 4; ++r) {
      s1[r] += __shfl_xor(s1[r], m, 64);
      s2[r] += __shfl_xor(s2[r], m, 64);
    }
  }
  if ((lane & 15) == 0) {
    float* pp = part + (size_t)bid * 128;
#pragma unroll
    for (int r = 0; r < 4; ++r) {
      pp[obase + r] = s1[r];
      pp[64 + obase + r] = s2[r];
    }
  }
}

// ---- BN finalize: reduce 4096-block partials, one block per channel ----
__global__ void kbnf(const float* __restrict__ part, const float* __restrict__ gamma,
                     const float* __restrict__ beta, float* __restrict__ stats) {
  __shared__ float r1[256], r2[256];
  int o = blockIdx.x;
  int tid = threadIdx.x;
  float s1 = 0.f, s2 = 0.f;
  for (int i = tid; i < 4096; i += 256) {
    s1 += part[(size_t)i * 128 + o];
    s2 += part[(size_t)i * 128 + 64 + o];
  }
  r1[tid] = s1; r2[tid] = s2;
  __syncthreads();
  for (int s = 128; s > 0; s >>= 1) {
    if (tid < s) { r1[tid] += r1[tid + s]; r2[tid] += r2[tid + s]; }
    __syncthreads();
  }
  if (tid == 0) {
    float m = r1[0] * (1.f / 131072.f);
    float v = r2[0] * (1.f / 131072.f) - m * m;
    float sc = gamma[o] * rsqrtf(v + 1e-5f);
    stats[128 + o] = sc;
    stats[192 + o] = beta[o] - m * sc;
  }
}

// ---- in-place scale/shift + PReLU on y (= d_out) ----
__global__ void kfinal(float* __restrict__ y, const float* __restrict__ stats,
                       const float* __restrict__ pa) {
  float a = pa[0];
  int total = NPIX * 64 / 4;
  for (int i = blockIdx.x * blockDim.x + threadIdx.x; i < total;
       i += gridDim.x * blockDim.x) {
    int o = (i >> 12) & 63;
    f32x4 v = ((const f32x4*)y)[i];
    float sc = stats[128 + o], sh = stats[192 + o];
#pragma unroll
    for (int j = 0; j < 4; ++j) {
      float t = fmaf(v[j], sc, sh);
      v[j] = t >= 0.f ? t : a * t;
    }
    ((f32x4*)y)[i] = v;
  }
}

extern "C" void kernel_launch(void* const* d_in, const int* in_sizes, int n_in,
                              void* d_out, int out_size, void* d_ws, size_t ws_size,
                              hipStream_t stream) {
  const float* x  = (const float*)d_in[0];
  const float* ow = (const float*)d_in[1];
  const float* ob = (const float*)d_in[2];
  const float* dw = (const float*)d_in[3];
  const float* db = (const float*)d_in[4];
  const float* gm = (const float*)d_in[5];
  const float* bt = (const float*)d_in[6];
  const float* pa = (const float*)d_in[7];
  char* ws = (char*)d_ws;
  u16*   xt    = (u16*)(ws + XT_OFF);
  float* part  = (float*)(ws + PART_OFF);
  u16*   Wb    = (u16*)(ws + WB_OFF);
  u16*   Wo    = (u16*)(ws + WO_OFF);
  float* stats = (float*)(ws + STATS_OFF);
  float* y = (float*)d_out;   // d_out doubles as the pre-BN activation buffer

  kprep<<<216, 256, 0, stream>>>(dw, ow, Wb, Wo);
  ktrans<<<2048, 256, 0, stream>>>(x, xt);
  kmain<<<4096, 256, 0, stream>>>(xt, Wo, ob, Wb, db, y, part);
  kbnf<<<64, 256, 0, stream>>>(part, gm, bt, stats);
  kfinal<<<2048, 256, 0, stream>>>(y, stats, pa);
}

// Round 18
// 98.108 us; speedup vs baseline: 2.7016x; 1.3556x over previous
//
#include <hip/hip_runtime.h>
#include <hip/hip_bf16.h>
#include <hip/hip_fp16.h>

typedef float f32x4 __attribute__((ext_vector_type(4)));
typedef unsigned int u32;
typedef u32 u32x4 __attribute__((ext_vector_type(4)));
typedef __bf16 bf16x8 __attribute__((ext_vector_type(8)));
typedef short s16x8 __attribute__((ext_vector_type(8)));
typedef unsigned short u16;

#define HWSZ 16384
#define NPIX 131072

// ws byte offsets
#define XT_OFF    0u          // u16(bf16)[NPIX*64]  x transposed to NHWC (16.78 MB)
#define PART_OFF  33554432u   // float[2048*128]  per-block BN partials (1 MB)
#define WB_OFF    42991616u   // u16(bf16)[64*576]  deform_w, [o][k2*64+c]
#define STATS_OFF 43106816u   // float[256]: (unused)[128], scale[64], shift[64]
#define WO_OFF    43107840u   // u16(bf16)[32*576]  offset_w padded, [oc][k2*64+c]

__device__ inline u32 pkbf(float lo, float hi) {
  u16 l = __builtin_bit_cast(u16, __float2bfloat16(lo));
  u16 h = __builtin_bit_cast(u16, __float2bfloat16(hi));
  return (u32)l | ((u32)h << 16);
}
__device__ inline float bflo(u32 u) { return __builtin_bit_cast(float, u << 16); }
__device__ inline float bfhi(u32 u) { return __builtin_bit_cast(float, u & 0xFFFF0000u); }

// ---- prep: reorder/convert weights to bf16 ----
__global__ void kprep(const float* __restrict__ dw, const float* __restrict__ ow,
                      u16* __restrict__ Wb, u16* __restrict__ Wo) {
  int t = blockIdx.x * 256 + threadIdx.x;
  if (t < 36864) {                      // deform_w (64,64,3,3) -> Wb[o][k2*64+c] bf16
    int o = t / 576, r = t % 576;
    int c = r / 9, k2 = r % 9;
    __hip_bfloat16 h = __float2bfloat16(dw[t]);
    Wb[o * 576 + k2 * 64 + c] = __builtin_bit_cast(u16, h);
  } else if (t < 55296) {               // offset_w (18,64,3,3) -> Wo[oc][k2*64+c], pad to 32
    int t2 = t - 36864;
    int oc = t2 / 576, r = t2 % 576;
    int c = r / 9, k2 = r % 9;
    float v = (oc < 18) ? ow[(oc * 64 + c) * 9 + k2] : 0.f;
    __hip_bfloat16 h = __float2bfloat16(v);
    Wo[oc * 576 + k2 * 64 + c] = __builtin_bit_cast(u16, h);
  }
}

// ---- NCHW f32 -> NHWC bf16 transpose of x (vectorized 16B stores) ----
__global__ void ktrans(const float* __restrict__ x, u16* __restrict__ xt) {
  __shared__ float tile[64][65];
  int blk = blockIdx.x;
  int b = blk >> 8, hwT = (blk & 255) * 64;
  int tid = threadIdx.x;
  int tx = tid & 63, ty = tid >> 6;
  const float* xp = x + (size_t)b * 64 * HWSZ;
#pragma unroll
  for (int r = 0; r < 16; ++r) {
    int c = r * 4 + ty;
    tile[c][tx] = xp[c * HWSZ + hwT + tx];
  }
  __syncthreads();
  u16* xo = xt + ((size_t)b * HWSZ + hwT) * 64;
  int o8 = (tid & 7) * 8;
#pragma unroll
  for (int r = 0; r < 2; ++r) {
    int hwl = r * 32 + (tid >> 3);
    u32x4 out;
#pragma unroll
    for (int j = 0; j < 4; ++j)
      out[j] = pkbf(tile[o8 + 2 * j][hwl], tile[o8 + 2 * j + 1][hwl]);
    *(u32x4*)&xo[(size_t)hwl * 64 + o8] = out;
  }
}

// ---- fused, tap-pipelined, 64-px tile: per-tap staging + MFMA accumulate ----
// block: 256 thr = 4 waves; tile = 64 pixels (weights/meta amortize 2x vs 32-px)
// LDS: S2 16384 + OFFT 5120 + mWp 4608 + mPos 2304 = 28416 B -> 5 blocks/CU
__global__ __launch_bounds__(256, 6) void kmain(
    const u16* __restrict__ xt, const u16* __restrict__ Wo,
    const float* __restrict__ offb, const u16* __restrict__ Wb,
    const float* __restrict__ db, float* __restrict__ y,
    float* __restrict__ part) {
  __shared__ u16 S2[2][64 * 64];       // per-tap staging, XOR-swizzled per 64ch row
  __shared__ float OFFT[64 * 20];
  __shared__ u32 mWp[576 * 2];         // per (pix,tap): f16x2 {w00,w01},{w10,w11}
  __shared__ u32 mPos[576];            // pixel_byte(×128) | dxs | dys<<1
  int tid = threadIdx.x;
  int lane = tid & 63, wid = tid >> 6;
  int bid = blockIdx.x;
  int batch = bid & 7, tilei = bid >> 3;
  int base = (batch << 14) + tilei * 64;
  int b = batch;
  int hw0 = base & 16383;
  int h0 = hw0 >> 7, w0 = hw0 & 127;   // 64-px tile lies within row h0

  int oct = lane & 7;
  int p0 = wid * 8 + (lane >> 3);      // this thread's pixels: p0 and p0+32
  int oct16 = oct << 4, oct8 = oct << 3;
  int q8 = (lane >> 4) * 8;
  const char* xb = (const char*)xt;

  // ---- phase 1: offset-conv GEMM, tap-pipelined ----
  // wave w: oc-block (w&1), px-blocks (w>>1)*2 + {0,1}
  int ocb2 = wid & 1, pxb2 = (wid >> 1) * 2;
  int orow_o = ocb2 * 16 + (lane & 15);
  f32x4 acco0 = {0.f, 0.f, 0.f, 0.f}, acco1 = {0.f, 0.f, 0.f, 0.f};
#pragma unroll
  for (int k = 0; k < 9; ++k) {
#pragma unroll
    for (int pi = 0; pi < 2; ++pi) {   // im2col tap k for both pixels
      int pp = p0 + pi * 32;
      int yy = h0 - 1 + k / 3, xx = w0 + pp - 1 + k % 3;
      bool v = ((unsigned)yy < 128u) && ((unsigned)xx < 128u);
      const char* pb =
          v ? xb + (size_t)(((b << 14) + yy * 128 + xx) * 128) + oct16 : xb;
      u32x4 g = *(const u32x4*)pb;
      u32 msk = v ? 0xFFFFFFFFu : 0u;
      u32x4 out;
#pragma unroll
      for (int j = 0; j < 4; ++j) out[j] = g[j] & msk;
      *(u32x4*)&S2[k & 1][(pp * 64 + oct8) ^ ((pp & 7) << 3)] = out;
    }
    __syncthreads();
#pragma unroll
    for (int h = 0; h < 2; ++h) {
      int kc = 2 * k + h;
      s16x8 a = *(const s16x8*)(Wo + orow_o * 576 + kc * 32 + q8);
      {
        int row = pxb2 * 16 + (lane & 15);
        int idx = (row * 64 + h * 32 + q8) ^ ((row & 7) << 3);
        bf16x8 bb = __builtin_bit_cast(bf16x8, *(const s16x8*)&S2[k & 1][idx]);
        acco0 = __builtin_amdgcn_mfma_f32_16x16x32_bf16(
            __builtin_bit_cast(bf16x8, a), bb, acco0, 0, 0, 0);
      }
      {
        int row = (pxb2 + 1) * 16 + (lane & 15);
        int idx = (row * 64 + h * 32 + q8) ^ ((row & 7) << 3);
        bf16x8 bb = __builtin_bit_cast(bf16x8, *(const s16x8*)&S2[k & 1][idx]);
        acco1 = __builtin_amdgcn_mfma_f32_16x16x32_bf16(
            __builtin_bit_cast(bf16x8, a), bb, acco1, 0, 0, 0);
      }
    }
  }
  __syncthreads();

  // ---- offs -> OFFT ----
#pragma unroll
  for (int t2 = 0; t2 < 2; ++t2) {
    int pixl = (pxb2 + t2) * 16 + (lane & 15);
    int ocb = ocb2 * 16 + (lane >> 4) * 4;
    f32x4 a = t2 ? acco1 : acco0;
#pragma unroll
    for (int r = 0; r < 4; ++r) {
      int oc = ocb + r;
      if (oc < 18) OFFT[pixl * 20 + oc] = a[r] + offb[oc];
    }
  }
  __syncthreads();

  // ---- meta: per-(pixel,tap), 576 tasks ----
  for (int t = tid; t < 576; t += 256) {
    int tp = t / 9, k2 = t - tp * 9;
    int pix = base + tp;
    int hw = pix & 16383;
    int hh = hw >> 7, ww = hw & 127;
    float dy = OFFT[tp * 20 + 2 * k2];
    float dx = OFFT[tp * 20 + 2 * k2 + 1];
    float sy = (float)(hh - 1 + k2 / 3) + dy;
    float sx = (float)(ww - 1 + k2 % 3) + dx;
    float fy = floorf(sy), fx = floorf(sx);
    int y0 = (int)fy, x0 = (int)fx;
    float wy1 = sy - fy, wx1 = sx - fx;
    float ay0 = ((unsigned)y0 < 128u) ? 1.f - wy1 : 0.f;
    float ay1 = ((unsigned)(y0 + 1) < 128u) ? wy1 : 0.f;
    float ax0 = ((unsigned)x0 < 128u) ? 1.f - wx1 : 0.f;
    float ax1 = ((unsigned)(x0 + 1) < 128u) ? wx1 : 0.f;
    int y0c = min(max(y0, 0), 127), x0c = min(max(x0, 0), 127);
    int dys = min(max(y0 + 1, 0), 127) - y0c;
    int dxs = min(max(x0 + 1, 0), 127) - x0c;
    mWp[t * 2]     = __builtin_bit_cast(u32, __floats2half2_rn(ay0 * ax0, ay0 * ax1));
    mWp[t * 2 + 1] = __builtin_bit_cast(u32, __floats2half2_rn(ay1 * ax0, ay1 * ax1));
    mPos[t] = (u32)(((b << 14) + y0c * 128 + x0c) * 128) | (u32)dxs | ((u32)dys << 1);
  }
  __syncthreads();

  // ---- phase 2: deform GEMM, tap-pipelined sampling ----
  // wave w: o-rows 16w..16w+15, all 4 px-blocks
  f32x4 acc[4];
#pragma unroll
  for (int nb = 0; nb < 4; ++nb) acc[nb] = {0.f, 0.f, 0.f, 0.f};
  int orow_d = wid * 16 + (lane & 15);
#pragma unroll
  for (int k = 0; k < 9; ++k) {
#pragma unroll
    for (int pi = 0; pi < 2; ++pi) {   // sample tap k for both pixels
      int pp = p0 + pi * 32;
      int t = pp * 9 + k;
      u32 wlo = mWp[t * 2], whi = mWp[t * 2 + 1];
      u32 pm = mPos[t];
      u32 dxB = (pm & 1u) << 7;        // 128 B x-step
      u32 dyB = (pm & 2u) << 13;       // 16384 B y-step
      const char* pb = xb + (pm & 0xFFFFFF80u) + oct16;
      u32x4 c00 = *(const u32x4*)pb;
      u32x4 c01 = *(const u32x4*)(pb + dxB);
      u32x4 c10 = *(const u32x4*)(pb + dyB);
      u32x4 c11 = *(const u32x4*)(pb + dyB + dxB);
      __half2 hl = __builtin_bit_cast(__half2, wlo);
      __half2 hh2 = __builtin_bit_cast(__half2, whi);
      float w00 = __low2float(hl), w01 = __high2float(hl);
      float w10 = __low2float(hh2), w11 = __high2float(hh2);
      u32x4 out;
#pragma unroll
      for (int j = 0; j < 4; ++j) {
        float sL = fmaf(w11, bflo(c11[j]), fmaf(w10, bflo(c10[j]),
                   fmaf(w01, bflo(c01[j]), w00 * bflo(c00[j]))));
        float sH = fmaf(w11, bfhi(c11[j]), fmaf(w10, bfhi(c10[j]),
                   fmaf(w01, bfhi(c01[j]), w00 * bfhi(c00[j]))));
        out[j] = pkbf(sL, sH);
      }
      *(u32x4*)&S2[k & 1][(pp * 64 + oct8) ^ ((pp & 7) << 3)] = out;
    }
    __syncthreads();
#pragma unroll
    for (int h = 0; h < 2; ++h) {
      int kc = 2 * k + h;
      s16x8 a = *(const s16x8*)(Wb + orow_d * 576 + kc * 32 + q8);
#pragma unroll
      for (int nb = 0; nb < 4; ++nb) {
        int row = nb * 16 + (lane & 15);
        int idx = (row * 64 + h * 32 + q8) ^ ((row & 7) << 3);
        bf16x8 bb = __builtin_bit_cast(bf16x8, *(const s16x8*)&S2[k & 1][idx]);
        acc[nb] = __builtin_amdgcn_mfma_f32_16x16x32_bf16(
            __builtin_bit_cast(bf16x8, a), bb, acc[nb], 0, 0, 0);
      }
    }
  }

  // ---- epilogue: y write + per-block BN partials (no atomics) ----
  int obase = wid * 16 + (lane >> 4) * 4;
  float s1[4] = {0, 0, 0, 0}, s2[4] = {0, 0, 0, 0};
#pragma unroll
  for (int nb = 0; nb < 4; ++nb) {
    int pix = base + nb * 16 + (lane & 15);
    int hw = pix & 16383;
    float* yp = y + (size_t)b * (64 * HWSZ) + hw;
#pragma unroll
    for (int r = 0; r < 4; ++r) {
      int o = obase + r;
      float v = acc[nb][r] + db[o];
      yp[(size_t)o * HWSZ] = v;
      s1[r] += v;
      s2[r] += v * v;
    }
  }
#pragma unroll
  for (int m = 1; m < 16; m <<= 1) {
#pragma unroll
    for (int r = 0; r < 4; ++r) {
      s1[r] += __shfl_xor(s1[r], m, 64);
      s2[r] += __shfl_xor(s2[r], m, 64);
    }
  }
  if ((lane & 15) == 0) {
    float* pp = part + (size_t)bid * 128;
#pragma unroll
    for (int r = 0; r < 4; ++r) {
      pp[obase + r] = s1[r];
      pp[64 + obase + r] = s2[r];
    }
  }
}

// ---- BN finalize: reduce 2048-block partials, one block per channel ----
__global__ void kbnf(const float* __restrict__ part, const float* __restrict__ gamma,
                     const float* __restrict__ beta, float* __restrict__ stats) {
  __shared__ float r1[256], r2[256];
  int o = blockIdx.x;
  int tid = threadIdx.x;
  float s1 = 0.f, s2 = 0.f;
  for (int i = tid; i < 2048; i += 256) {
    s1 += part[(size_t)i * 128 + o];
    s2 += part[(size_t)i * 128 + 64 + o];
  }
  r1[tid] = s1; r2[tid] = s2;
  __syncthreads();
  for (int s = 128; s > 0; s >>= 1) {
    if (tid < s) { r1[tid] += r1[tid + s]; r2[tid] += r2[tid + s]; }
    __syncthreads();
  }
  if (tid == 0) {
    float m = r1[0] * (1.f / 131072.f);
    float v = r2[0] * (1.f / 131072.f) - m * m;
    float sc = gamma[o] * rsqrtf(v + 1e-5f);
    stats[128 + o] = sc;
    stats[192 + o] = beta[o] - m * sc;
  }
}

// ---- in-place scale/shift + PReLU on y (= d_out) ----
__global__ void kfinal(float* __restrict__ y, const float* __restrict__ stats,
                       const float* __restrict__ pa) {
  float a = pa[0];
  int total = NPIX * 64 / 4;
  for (int i = blockIdx.x * blockDim.x + threadIdx.x; i < total;
       i += gridDim.x * blockDim.x) {
    int o = (i >> 12) & 63;
    f32x4 v = ((const f32x4*)y)[i];
    float sc = stats[128 + o], sh = stats[192 + o];
#pragma unroll
    for (int j = 0; j < 4; ++j) {
      float t = fmaf(v[j], sc, sh);
      v[j] = t >= 0.f ? t : a * t;
    }
    ((f32x4*)y)[i] = v;
  }
}

extern "C" void kernel_launch(void* const* d_in, const int* in_sizes, int n_in,
                              void* d_out, int out_size, void* d_ws, size_t ws_size,
                              hipStream_t stream) {
  const float* x  = (const float*)d_in[0];
  const float* ow = (const float*)d_in[1];
  const float* ob = (const float*)d_in[2];
  const float* dw = (const float*)d_in[3];
  const float* db = (const float*)d_in[4];
  const float* gm = (const float*)d_in[5];
  const float* bt = (const float*)d_in[6];
  const float* pa = (const float*)d_in[7];
  char* ws = (char*)d_ws;
  u16*   xt    = (u16*)(ws + XT_OFF);
  float* part  = (float*)(ws + PART_OFF);
  u16*   Wb    = (u16*)(ws + WB_OFF);
  u16*   Wo    = (u16*)(ws + WO_OFF);
  float* stats = (float*)(ws + STATS_OFF);
  float* y = (float*)d_out;   // d_out doubles as the pre-BN activation buffer

  kprep<<<216, 256, 0, stream>>>(dw, ow, Wb, Wo);
  ktrans<<<2048, 256, 0, stream>>>(x, xt);
  kmain<<<2048, 256, 0, stream>>>(xt, Wo, ob, Wb, db, y, part);
  kbnf<<<64, 256, 0, stream>>>(part, gm, bt, stats);
  kfinal<<<2048, 256, 0, stream>>>(y, stats, pa);
}

// Round 19
// 97.917 us; speedup vs baseline: 2.7069x; 1.0020x over previous
//
#include <hip/hip_runtime.h>
#include <hip/hip_bf16.h>
#include <hip/hip_fp16.h>

typedef float f32x4 __attribute__((ext_vector_type(4)));
typedef unsigned int u32;
typedef u32 u32x4 __attribute__((ext_vector_type(4)));
typedef __bf16 bf16x8 __attribute__((ext_vector_type(8)));
typedef short s16x8 __attribute__((ext_vector_type(8)));
typedef unsigned short u16;

#define HWSZ 16384
#define NPIX 131072

// ws byte offsets
#define XT_OFF    0u          // u16(bf16)[NPIX*64]  x transposed to NHWC (16.78 MB)
#define PART_OFF  33554432u   // float[2048*128]  per-block BN partials (1 MB)
#define WB_OFF    42991616u   // u16(bf16)[64*576]  deform_w, [o][k2*64+c]
#define STATS_OFF 43106816u   // float[256]: (unused)[128], scale[64], shift[64]
#define WO_OFF    43107840u   // u16(bf16)[32*576]  offset_w padded, [oc][k2*64+c]

__device__ inline u32 pkbf(float lo, float hi) {
  u16 l = __builtin_bit_cast(u16, __float2bfloat16(lo));
  u16 h = __builtin_bit_cast(u16, __float2bfloat16(hi));
  return (u32)l | ((u32)h << 16);
}
__device__ inline float bflo(u32 u) { return __builtin_bit_cast(float, u << 16); }
__device__ inline float bfhi(u32 u) { return __builtin_bit_cast(float, u & 0xFFFF0000u); }

// ---- prep: reorder/convert weights to bf16 ----
__global__ void kprep(const float* __restrict__ dw, const float* __restrict__ ow,
                      u16* __restrict__ Wb, u16* __restrict__ Wo) {
  int t = blockIdx.x * 256 + threadIdx.x;
  if (t < 36864) {                      // deform_w (64,64,3,3) -> Wb[o][k2*64+c] bf16
    int o = t / 576, r = t % 576;
    int c = r / 9, k2 = r % 9;
    __hip_bfloat16 h = __float2bfloat16(dw[t]);
    Wb[o * 576 + k2 * 64 + c] = __builtin_bit_cast(u16, h);
  } else if (t < 55296) {               // offset_w (18,64,3,3) -> Wo[oc][k2*64+c], pad to 32
    int t2 = t - 36864;
    int oc = t2 / 576, r = t2 % 576;
    int c = r / 9, k2 = r % 9;
    float v = (oc < 18) ? ow[(oc * 64 + c) * 9 + k2] : 0.f;
    __hip_bfloat16 h = __float2bfloat16(v);
    Wo[oc * 576 + k2 * 64 + c] = __builtin_bit_cast(u16, h);
  }
}

// ---- NCHW f32 -> NHWC bf16 transpose of x (vectorized 16B stores) ----
__global__ void ktrans(const float* __restrict__ x, u16* __restrict__ xt) {
  __shared__ float tile[64][65];
  int blk = blockIdx.x;
  int b = blk >> 8, hwT = (blk & 255) * 64;
  int tid = threadIdx.x;
  int tx = tid & 63, ty = tid >> 6;
  const float* xp = x + (size_t)b * 64 * HWSZ;
#pragma unroll
  for (int r = 0; r < 16; ++r) {
    int c = r * 4 + ty;
    tile[c][tx] = xp[c * HWSZ + hwT + tx];
  }
  __syncthreads();
  u16* xo = xt + ((size_t)b * HWSZ + hwT) * 64;
  int o8 = (tid & 7) * 8;
#pragma unroll
  for (int r = 0; r < 2; ++r) {
    int hwl = r * 32 + (tid >> 3);
    u32x4 out;
#pragma unroll
    for (int j = 0; j < 4; ++j)
      out[j] = pkbf(tile[o8 + 2 * j][hwl], tile[o8 + 2 * j + 1][hwl]);
    *(u32x4*)&xo[(size_t)hwl * 64 + o8] = out;
  }
}

// ---- fused, tap-pipelined w/ register prefetch across barriers ----
// block: 256 thr = 4 waves; tile = 64 pixels
// LDS: S2 16384 + mWp 4608 + mPos 2304 = 23296 B (OFFT aliases S2[0])
__global__ __launch_bounds__(256, 4) void kmain(
    const u16* __restrict__ xt, const u16* __restrict__ Wo,
    const float* __restrict__ offb, const u16* __restrict__ Wb,
    const float* __restrict__ db, float* __restrict__ y,
    float* __restrict__ part) {
  __shared__ u16 S2[2][64 * 64];       // per-tap staging, XOR-swizzled per 64ch row
  __shared__ u32 mWp[576 * 2];         // per (pix,tap): f16x2 {w00,w01},{w10,w11}
  __shared__ u32 mPos[576];            // pixel_byte(×128) | dxs | dys<<1
  float* OFFT = (float*)&S2[0][0];     // [64][20] floats, aliases S2[0] (phase-separated)
  int tid = threadIdx.x;
  int lane = tid & 63, wid = tid >> 6;
  int bid = blockIdx.x;
  int batch = bid & 7, tilei = bid >> 3;
  int base = (batch << 14) + tilei * 64;
  int b = batch;
  int hw0 = base & 16383;
  int h0 = hw0 >> 7, w0 = hw0 & 127;   // 64-px tile lies within row h0

  int oct = lane & 7;
  int p0 = wid * 8 + (lane >> 3);      // this thread's pixels: p0 and p0+32
  int oct16 = oct << 4, oct8 = oct << 3;
  int q8 = (lane >> 4) * 8;
  const char* xb = (const char*)xt;

  // ---- phase 1: offset-conv GEMM, tap-pipelined w/ depth-1 prefetch ----
  int ocb2 = wid & 1, pxb2 = (wid >> 1) * 2;
  int orow_o = ocb2 * 16 + (lane & 15);
  f32x4 acco0 = {0.f, 0.f, 0.f, 0.f}, acco1 = {0.f, 0.f, 0.f, 0.f};

  auto im_load = [&](int k, u32x4 (&g)[2], u32 (&m)[2]) {
#pragma unroll
    for (int pi = 0; pi < 2; ++pi) {
      int pp = p0 + pi * 32;
      int yy = h0 - 1 + k / 3, xx = w0 + pp - 1 + k % 3;
      bool v = ((unsigned)yy < 128u) && ((unsigned)xx < 128u);
      const char* pb =
          v ? xb + (size_t)(((b << 14) + yy * 128 + xx) * 128) + oct16 : xb;
      g[pi] = *(const u32x4*)pb;
      m[pi] = v ? 0xFFFFFFFFu : 0u;
    }
  };
  auto im_store = [&](int k, const u32x4 (&g)[2], const u32 (&m)[2]) {
#pragma unroll
    for (int pi = 0; pi < 2; ++pi) {
      int pp = p0 + pi * 32;
      u32x4 out;
#pragma unroll
      for (int j = 0; j < 4; ++j) out[j] = g[pi][j] & m[pi];
      *(u32x4*)&S2[k & 1][(pp * 64 + oct8) ^ ((pp & 7) << 3)] = out;
    }
  };

  {
    u32x4 gA[2], gB[2];
    u32 mA[2], mB[2];
    im_load(0, gA, mA);
#pragma unroll
    for (int k = 0; k < 9; ++k) {
      if (k & 1) {
        if (k < 8) im_load(k + 1, gA, mA);
        im_store(k, gB, mB);
      } else {
        if (k < 8) im_load(k + 1, gB, mB);
        im_store(k, gA, mA);
      }
      __syncthreads();
#pragma unroll
      for (int h = 0; h < 2; ++h) {
        int kc = 2 * k + h;
        s16x8 a = *(const s16x8*)(Wo + orow_o * 576 + kc * 32 + q8);
        {
          int row = pxb2 * 16 + (lane & 15);
          int idx = (row * 64 + h * 32 + q8) ^ ((row & 7) << 3);
          bf16x8 bb = __builtin_bit_cast(bf16x8, *(const s16x8*)&S2[k & 1][idx]);
          acco0 = __builtin_amdgcn_mfma_f32_16x16x32_bf16(
              __builtin_bit_cast(bf16x8, a), bb, acco0, 0, 0, 0);
        }
        {
          int row = (pxb2 + 1) * 16 + (lane & 15);
          int idx = (row * 64 + h * 32 + q8) ^ ((row & 7) << 3);
          bf16x8 bb = __builtin_bit_cast(bf16x8, *(const s16x8*)&S2[k & 1][idx]);
          acco1 = __builtin_amdgcn_mfma_f32_16x16x32_bf16(
              __builtin_bit_cast(bf16x8, a), bb, acco1, 0, 0, 0);
        }
      }
    }
  }
  __syncthreads();                     // S2 dead; OFFT may now be written

  // ---- offs -> OFFT (aliases S2[0]) ----
#pragma unroll
  for (int t2 = 0; t2 < 2; ++t2) {
    int pixl = (pxb2 + t2) * 16 + (lane & 15);
    int ocb = ocb2 * 16 + (lane >> 4) * 4;
    f32x4 a = t2 ? acco1 : acco0;
#pragma unroll
    for (int r = 0; r < 4; ++r) {
      int oc = ocb + r;
      if (oc < 18) OFFT[pixl * 20 + oc] = a[r] + offb[oc];
    }
  }
  __syncthreads();

  // ---- meta: per-(pixel,tap), 576 tasks ----
  for (int t = tid; t < 576; t += 256) {
    int tp = t / 9, k2 = t - tp * 9;
    int pix = base + tp;
    int hw = pix & 16383;
    int hh = hw >> 7, ww = hw & 127;
    float dy = OFFT[tp * 20 + 2 * k2];
    float dx = OFFT[tp * 20 + 2 * k2 + 1];
    float sy = (float)(hh - 1 + k2 / 3) + dy;
    float sx = (float)(ww - 1 + k2 % 3) + dx;
    float fy = floorf(sy), fx = floorf(sx);
    int y0 = (int)fy, x0 = (int)fx;
    float wy1 = sy - fy, wx1 = sx - fx;
    float ay0 = ((unsigned)y0 < 128u) ? 1.f - wy1 : 0.f;
    float ay1 = ((unsigned)(y0 + 1) < 128u) ? wy1 : 0.f;
    float ax0 = ((unsigned)x0 < 128u) ? 1.f - wx1 : 0.f;
    float ax1 = ((unsigned)(x0 + 1) < 128u) ? wx1 : 0.f;
    int y0c = min(max(y0, 0), 127), x0c = min(max(x0, 0), 127);
    int dys = min(max(y0 + 1, 0), 127) - y0c;
    int dxs = min(max(x0 + 1, 0), 127) - x0c;
    mWp[t * 2]     = __builtin_bit_cast(u32, __floats2half2_rn(ay0 * ax0, ay0 * ax1));
    mWp[t * 2 + 1] = __builtin_bit_cast(u32, __floats2half2_rn(ay1 * ax0, ay1 * ax1));
    mPos[t] = (u32)(((b << 14) + y0c * 128 + x0c) * 128) | (u32)dxs | ((u32)dys << 1);
  }
  __syncthreads();                     // meta done; S2[0] (OFFT) may be overwritten

  // ---- phase 2: deform GEMM, tap-pipelined sampling w/ depth-1 prefetch ----
  f32x4 acc[4];
#pragma unroll
  for (int nb = 0; nb < 4; ++nb) acc[nb] = {0.f, 0.f, 0.f, 0.f};
  int orow_d = wid * 16 + (lane & 15);

  auto tap_load = [&](int k, u32x4 (&c)[2][4], u32 (&wl)[2], u32 (&wh)[2]) {
#pragma unroll
    for (int pi = 0; pi < 2; ++pi) {
      int pp = p0 + pi * 32;
      int t = pp * 9 + k;
      wl[pi] = mWp[t * 2];
      wh[pi] = mWp[t * 2 + 1];
      u32 pm = mPos[t];
      u32 dxB = (pm & 1u) << 7;        // 128 B x-step
      u32 dyB = (pm & 2u) << 13;       // 16384 B y-step
      const char* pb = xb + (pm & 0xFFFFFF80u) + oct16;
      c[pi][0] = *(const u32x4*)pb;
      c[pi][1] = *(const u32x4*)(pb + dxB);
      c[pi][2] = *(const u32x4*)(pb + dyB);
      c[pi][3] = *(const u32x4*)(pb + dyB + dxB);
    }
  };
  auto tap_store = [&](int k, const u32x4 (&c)[2][4], const u32 (&wl)[2],
                       const u32 (&wh)[2]) {
#pragma unroll
    for (int pi = 0; pi < 2; ++pi) {
      int pp = p0 + pi * 32;
      __half2 hl = __builtin_bit_cast(__half2, wl[pi]);
      __half2 hh2 = __builtin_bit_cast(__half2, wh[pi]);
      float w00 = __low2float(hl), w01 = __high2float(hl);
      float w10 = __low2float(hh2), w11 = __high2float(hh2);
      u32x4 out;
#pragma unroll
      for (int j = 0; j < 4; ++j) {
        float sL = fmaf(w11, bflo(c[pi][3][j]), fmaf(w10, bflo(c[pi][2][j]),
                   fmaf(w01, bflo(c[pi][1][j]), w00 * bflo(c[pi][0][j]))));
        float sH = fmaf(w11, bfhi(c[pi][3][j]), fmaf(w10, bfhi(c[pi][2][j]),
                   fmaf(w01, bfhi(c[pi][1][j]), w00 * bfhi(c[pi][0][j]))));
        out[j] = pkbf(sL, sH);
      }
      *(u32x4*)&S2[k & 1][(pp * 64 + oct8) ^ ((pp & 7) << 3)] = out;
    }
  };

  {
    u32x4 cA[2][4], cB[2][4];
    u32 wlA[2], whA[2], wlB[2], whB[2];
    tap_load(0, cA, wlA, whA);
#pragma unroll
    for (int k = 0; k < 9; ++k) {
      if (k & 1) {
        if (k < 8) tap_load(k + 1, cA, wlA, whA);
        tap_store(k, cB, wlB, whB);
      } else {
        if (k < 8) tap_load(k + 1, cB, wlB, whB);
        tap_store(k, cA, wlA, whA);
      }
      __syncthreads();
#pragma unroll
      for (int h = 0; h < 2; ++h) {
        int kc = 2 * k + h;
        s16x8 a = *(const s16x8*)(Wb + orow_d * 576 + kc * 32 + q8);
#pragma unroll
        for (int nb = 0; nb < 4; ++nb) {
          int row = nb * 16 + (lane & 15);
          int idx = (row * 64 + h * 32 + q8) ^ ((row & 7) << 3);
          bf16x8 bb = __builtin_bit_cast(bf16x8, *(const s16x8*)&S2[k & 1][idx]);
          acc[nb] = __builtin_amdgcn_mfma_f32_16x16x32_bf16(
              __builtin_bit_cast(bf16x8, a), bb, acc[nb], 0, 0, 0);
        }
      }
    }
  }

  // ---- epilogue: y write + per-block BN partials (no atomics) ----
  int obase = wid * 16 + (lane >> 4) * 4;
  float s1[4] = {0, 0, 0, 0}, s2[4] = {0, 0, 0, 0};
#pragma unroll
  for (int nb = 0; nb < 4; ++nb) {
    int pix = base + nb * 16 + (lane & 15);
    int hw = pix & 16383;
    float* yp = y + (size_t)b * (64 * HWSZ) + hw;
#pragma unroll
    for (int r = 0; r < 4; ++r) {
      int o = obase + r;
      float v = acc[nb][r] + db[o];
      yp[(size_t)o * HWSZ] = v;
      s1[r] += v;
      s2[r] += v * v;
    }
  }
#pragma unroll
  for (int m = 1; m < 16; m <<= 1) {
#pragma unroll
    for (int r = 0; r < 4; ++r) {
      s1[r] += __shfl_xor(s1[r], m, 64);
      s2[r] += __shfl_xor(s2[r], m, 64);
    }
  }
  if ((lane & 15) == 0) {
    float* pp = part + (size_t)bid * 128;
#pragma unroll
    for (int r = 0; r < 4; ++r) {
      pp[obase + r] = s1[r];
      pp[64 + obase + r] = s2[r];
    }
  }
}

// ---- BN finalize: reduce 2048-block partials, one block per channel ----
__global__ void kbnf(const float* __restrict__ part, const float* __restrict__ gamma,
                     const float* __restrict__ beta, float* __restrict__ stats) {
  __shared__ float r1[256], r2[256];
  int o = blockIdx.x;
  int tid = threadIdx.x;
  float s1 = 0.f, s2 = 0.f;
  for (int i = tid; i < 2048; i += 256) {
    s1 += part[(size_t)i * 128 + o];
    s2 += part[(size_t)i * 128 + 64 + o];
  }
  r1[tid] = s1; r2[tid] = s2;
  __syncthreads();
  for (int s = 128; s > 0; s >>= 1) {
    if (tid < s) { r1[tid] += r1[tid + s]; r2[tid] += r2[tid + s]; }
    __syncthreads();
  }
  if (tid == 0) {
    float m = r1[0] * (1.f / 131072.f);
    float v = r2[0] * (1.f / 131072.f) - m * m;
    float sc = gamma[o] * rsqrtf(v + 1e-5f);
    stats[128 + o] = sc;
    stats[192 + o] = beta[o] - m * sc;
  }
}

// ---- in-place scale/shift + PReLU on y (= d_out) ----
__global__ void kfinal(float* __restrict__ y, const float* __restrict__ stats,
                       const float* __restrict__ pa) {
  float a = pa[0];
  int total = NPIX * 64 / 4;
  for (int i = blockIdx.x * blockDim.x + threadIdx.x; i < total;
       i += gridDim.x * blockDim.x) {
    int o = (i >> 12) & 63;
    f32x4 v = ((const f32x4*)y)[i];
    float sc = stats[128 + o], sh = stats[192 + o];
#pragma unroll
    for (int j = 0; j < 4; ++j) {
      float t = fmaf(v[j], sc, sh);
      v[j] = t >= 0.f ? t : a * t;
    }
    ((f32x4*)y)[i] = v;
  }
}

extern "C" void kernel_launch(void* const* d_in, const int* in_sizes, int n_in,
                              void* d_out, int out_size, void* d_ws, size_t ws_size,
                              hipStream_t stream) {
  const float* x  = (const float*)d_in[0];
  const float* ow = (const float*)d_in[1];
  const float* ob = (const float*)d_in[2];
  const float* dw = (const float*)d_in[3];
  const float* db = (const float*)d_in[4];
  const float* gm = (const float*)d_in[5];
  const float* bt = (const float*)d_in[6];
  const float* pa = (const float*)d_in[7];
  char* ws = (char*)d_ws;
  u16*   xt    = (u16*)(ws + XT_OFF);
  float* part  = (float*)(ws + PART_OFF);
  u16*   Wb    = (u16*)(ws + WB_OFF);
  u16*   Wo    = (u16*)(ws + WO_OFF);
  float* stats = (float*)(ws + STATS_OFF);
  float* y = (float*)d_out;   // d_out doubles as the pre-BN activation buffer

  kprep<<<216, 256, 0, stream>>>(dw, ow, Wb, Wo);
  ktrans<<<2048, 256, 0, stream>>>(x, xt);
  kmain<<<2048, 256, 0, stream>>>(xt, Wo, ob, Wb, db, y, part);
  kbnf<<<64, 256, 0, stream>>>(part, gm, bt, stats);
  kfinal<<<2048, 256, 0, stream>>>(y, stats, pa);
}